// Round 1
// baseline (646.039 us; speedup 1.0000x reference)
//
#include <hip/hip_runtime.h>
#include <math.h>

// ---------------------------------------------------------------------------
// MPNNPropPred: N=20000 nodes, E=50000 edges, B=128 graphs, H=64,
// FEAT=28, N_TYPES=100, EDGE_DIM=5, MP_ITER=3, S2S_IT=4. All f32.
// R5: single persistent kernel. 14 dispatches -> 1; software grid barrier
//     (generation counter + __threadfence for cross-XCD visibility).
//     Phases: A(setup: edgemats|wT|embed|hist|starts|zero) | P(place) |
//     M1..M3(root+msg fused via atomics into zeroed buffer, next buffer
//     zeroed concurrently) | S2S (blocks 0 mod 4). 5 grid barriers total.
//     Root folded into msg phase as one extra atomic matvec per node.
// ---------------------------------------------------------------------------

#define NN 20000
#define NE 50000
#define NB 128
#define HD 64
#define NFEAT 28
#define NTYPES 100
#define EDIM 5
#define MPIT 3
#define S2SIT 4
#define SMAX 224                  // nodes cached in LDS (max graph ~195 expected)
#define HP (HD + 1)               // padded LDS row stride

// persistent device globals: barrier is generation-based (g_gen monotonic
// across graph replays, g_cnt returns to 0 by invariant); hist/cur are
// restored to 0 at the end of each run by the last block.
__device__ int g_cnt = 0;
__device__ unsigned int g_gen = 0u;
__device__ int g_hist[EDIM] = {0, 0, 0, 0, 0};
__device__ int g_cur[EDIM]  = {0, 0, 0, 0, 0};

__device__ __forceinline__ float sigm(float x) {
  return 1.0f / (1.0f + expf(-x));
}

// grid-wide barrier. __threadfence (agent seq_cst) emits the L2 wb/inv pair
// required for non-atomic data visibility across XCDs. The relaxed g_gen
// load cannot sink below the acq_rel fetch_add (release semantics), so the
// observed generation is always the pre-arrival one.
__device__ __forceinline__ void gridbar(int nblk) {
  __syncthreads();
  if (threadIdx.x == 0) {
    __threadfence();
    unsigned int g = __hip_atomic_load(&g_gen, __ATOMIC_RELAXED, __HIP_MEMORY_SCOPE_AGENT);
    int a = __hip_atomic_fetch_add(&g_cnt, 1, __ATOMIC_ACQ_REL, __HIP_MEMORY_SCOPE_AGENT);
    if (a == nblk - 1) {
      __hip_atomic_store(&g_cnt, 0, __ATOMIC_RELAXED, __HIP_MEMORY_SCOPE_AGENT);
      __hip_atomic_fetch_add(&g_gen, 1u, __ATOMIC_RELEASE, __HIP_MEMORY_SCOPE_AGENT);
    } else {
      while (__hip_atomic_load(&g_gen, __ATOMIC_RELAXED, __HIP_MEMORY_SCOPE_AGENT) == g)
        __builtin_amdgcn_s_sleep(8);
    }
    __threadfence();
  }
  __syncthreads();
}

extern "C" __global__ __launch_bounds__(256, 2) void k_mega(
    const float* __restrict__ feat, const int* __restrict__ ntype,
    const int* __restrict__ ei, const int* __restrict__ etype,
    const int* __restrict__ batch,
    const float* __restrict__ W_emb, const float* __restrict__ b_emb,
    const float* __restrict__ W_e1, const float* __restrict__ b_e1,
    const float* __restrict__ W_e2, const float* __restrict__ b_e2,
    const float* __restrict__ roots, const float* __restrict__ conv_bias,
    const float* __restrict__ W_ih, const float* __restrict__ W_hh,
    const float* __restrict__ b_ih, const float* __restrict__ b_hh,
    const float* __restrict__ W_o1, const float* __restrict__ b_o1,
    const float* __restrict__ W_o2, const float* __restrict__ b_o2,
    float* __restrict__ Wty, float* __restrict__ hA, float* __restrict__ hB,
    float* __restrict__ hC, float* __restrict__ W_ihT, float* __restrict__ W_hhT,
    int* __restrict__ srcs, int* __restrict__ dsts, int* __restrict__ gstart,
    float* __restrict__ out) {
  // static LDS (62.5 KB -> 2 blocks/CU). s_hxs doubles as edgemats scratch.
  __shared__ float s_hs[SMAX * HP];
  __shared__ float s_ebuf[SMAX];
  __shared__ float s_qstar[2 * HD];
  __shared__ float s_hxs[HD], s_cxs[HD], s_gates[4 * HD];
  __shared__ float s_redM[4], s_redS[4], s_redR[4][HD];
  __shared__ float s_hid[HD];

  const int tid = threadIdx.x;
  const int lane = tid & 63;
  const int wv = tid >> 6;
  const int blk = blockIdx.x;
  const int nblk = gridDim.x;
  const int nthr = nblk << 8;
  const int gtid = (blk << 8) + tid;
  const int gw = (blk << 2) + wv;
  const int nwave = nblk << 2;

  // ============================ phase A ===================================
  // A1: 5 edge-type weight matrices (block-units 0..19; s_hxs = relu vec)
  for (int u = blk; u < EDIM * 4; u += nblk) {
    int t = u >> 2, ch = u & 3;
    if (tid < HD) {
      float x = W_e1[t * HD + tid] + b_e1[tid];
      s_hxs[tid] = x > 0.f ? x : 0.f;
    }
    __syncthreads();
    #pragma unroll
    for (int i = 0; i < 4; ++i) {
      int m = ch * 1024 + i * 256 + tid;
      float acc = b_e2[m];
      #pragma unroll
      for (int j = 0; j < HD; ++j) acc = fmaf(s_hxs[j], W_e2[j * 4096 + m], acc);
      Wty[t * 4096 + m] = acc;
    }
    __syncthreads();
  }

  // A2: LSTM weight transposes, coalesced on the write side
  for (int o = gtid; o < 2 * HD * 4 * HD; o += nthr)       // W_ihT [128][256]
    W_ihT[o] = W_ih[(o & 255) * 128 + (o >> 8)];
  for (int o = gtid; o < HD * 4 * HD; o += nthr)           // W_hhT [64][256]
    W_hhT[o] = W_hh[(o & 255) * 64 + (o >> 8)];

  // A3: node embedding, wave per node; feature-row weights hoisted to VGPRs
  {
    float wf[NFEAT];
    #pragma unroll
    for (int f = 0; f < NFEAT; ++f) wf[f] = W_emb[(NTYPES + f) * HD + lane];
    float bb = b_emb[lane];
    for (int n = gw; n < NN; n += nwave) {
      int nu = __builtin_amdgcn_readfirstlane(n);
      int t = __builtin_amdgcn_readfirstlane(ntype[nu]);
      const float* row = feat + nu * NFEAT;        // wave-uniform -> s_load
      float acc = bb + W_emb[t * HD + lane];
      #pragma unroll
      for (int f = 0; f < NFEAT; ++f) acc = fmaf(row[f], wf[f], acc);
      hA[nu * HD + lane] = acc;
    }
  }

  // A4: edge-type histogram (ballot-aggregated device atomics)
  for (int b0 = gw; (b0 << 6) < NE; b0 += nwave) {
    int e = (b0 << 6) + lane;
    int ty = (e < NE) ? etype[e] : -1;
    #pragma unroll
    for (int t = 0; t < EDIM; ++t) {
      unsigned long long mask = __ballot(ty == t);
      if (lane == 0 && mask) atomicAdd(&g_hist[t], __popcll(mask));
    }
  }

  // A5: CSR starts for sorted batch vector
  for (int n = gtid; n < NN; n += nthr) {
    int b = batch[n];
    if (n == 0)
      for (int t = 0; t <= b; ++t) gstart[t] = 0;
    int bn = (n + 1 < NN) ? batch[n + 1] : NB;
    for (int t = b + 1; t <= bn; ++t) gstart[t] = n + 1;
  }

  // A6: zero hB (M1 target)
  {
    float4 z = make_float4(0.f, 0.f, 0.f, 0.f);
    for (int i = gtid; i < NN * HD / 4; i += nthr)
      reinterpret_cast<float4*>(hB)[i] = z;
  }

  gridbar(nblk);   // ---- barrier 1: A -> P ----

  // type offsets (g_hist stays valid until restored at the very end)
  int offs[EDIM + 1];
  {
    int h0 = g_hist[0], h1 = g_hist[1], h2 = g_hist[2], h3 = g_hist[3], h4 = g_hist[4];
    offs[0] = 0;
    offs[1] = h0;
    offs[2] = h0 + h1;
    offs[3] = h0 + h1 + h2;
    offs[4] = h0 + h1 + h2 + h3;
    offs[5] = h0 + h1 + h2 + h3 + h4;
  }

  // ============================ phase P ===================================
  // place edges grouped by type (order within a type is irrelevant)
  for (int b0 = gw; (b0 << 6) < NE; b0 += nwave) {
    int e = (b0 << 6) + lane;
    int ty = (e < NE) ? etype[e] : -1;
    int sv = 0, dv = 0;
    if (e < NE) { sv = ei[e]; dv = ei[NE + e]; }
    #pragma unroll
    for (int t = 0; t < EDIM; ++t) {
      unsigned long long mask = __ballot(ty == t);
      if (mask == 0ull) continue;
      int base = 0;
      if (lane == 0) base = atomicAdd(&g_cur[t], __popcll(mask));
      base = __shfl(base, 0, 64);
      if (ty == t) {
        int pos = offs[t] + base + __popcll(mask & ((1ull << lane) - 1ull));
        srcs[pos] = sv;
        dsts[pos] = dv;
      }
    }
  }

  gridbar(nblk);   // ---- barrier 2: P -> M1 ----

  // ============================ phases M1..M3 =============================
  // edge waves do per-edge matvec h[src] @ W_type; node waves do the NNConv
  // root matvec + bias; both atomicAdd into the zero-initialized target.
  const int ew = (nwave * 5) / 7;          // ~edge share of 70000 matvec units
  const int eper = (NE + ew - 1) / ew;
  const int nnw = nwave - ew;

  #pragma unroll
  for (int it = 0; it < MPIT; ++it) {
    const float* __restrict__ hsrc = (it == 0) ? hA : (it == 1) ? hB : hC;
    float* __restrict__ htgt = (it == 0) ? hB : (it == 1) ? hC : hA;
    float* hzero = (it == 0) ? hC : (it == 1) ? hA : (float*)0;
    if (hzero) {                           // zero next iteration's target now
      float4 z = make_float4(0.f, 0.f, 0.f, 0.f);
      for (int i = gtid; i < NN * HD / 4; i += nthr)
        reinterpret_cast<float4*>(hzero)[i] = z;
    }
    if (gw < ew) {
      int beg = gw * eper;
      int end = beg + eper; if (end > NE) end = NE;
      #pragma unroll
      for (int t = 0; t < EDIM; ++t) {
        int lo = offs[t]     > beg ? offs[t]     : beg;
        int hi = offs[t + 1] < end ? offs[t + 1] : end;
        if (lo >= hi) continue;
        float w[HD];
        #pragma unroll
        for (int k = 0; k < HD; ++k) w[k] = Wty[t * 4096 + k * HD + lane];
        for (int p = lo; p < hi; ++p) {
          int s = __builtin_amdgcn_readfirstlane(srcs[p]);
          int d = __builtin_amdgcn_readfirstlane(dsts[p]);
          const float* row = hsrc + s * HD;     // wave-uniform -> s_load
          float a0 = 0.f, a1 = 0.f, a2 = 0.f, a3 = 0.f;
          #pragma unroll
          for (int k = 0; k < HD; k += 4) {
            a0 = fmaf(row[k + 0], w[k + 0], a0);
            a1 = fmaf(row[k + 1], w[k + 1], a1);
            a2 = fmaf(row[k + 2], w[k + 2], a2);
            a3 = fmaf(row[k + 3], w[k + 3], a3);
          }
          atomicAdd(&htgt[d * HD + lane], (a0 + a1) + (a2 + a3));
        }
      }
    } else {
      float w[HD];
      #pragma unroll
      for (int k = 0; k < HD; ++k) w[k] = roots[it * HD * HD + k * HD + lane];
      float bb = conv_bias[it * HD + lane];
      for (int n = gw - ew; n < NN; n += nnw) {
        int nu = __builtin_amdgcn_readfirstlane(n);
        const float* row = hsrc + nu * HD;      // wave-uniform -> s_load
        float a0 = bb, a1 = 0.f, a2 = 0.f, a3 = 0.f;
        #pragma unroll
        for (int k = 0; k < HD; k += 4) {
          a0 = fmaf(row[k + 0], w[k + 0], a0);
          a1 = fmaf(row[k + 1], w[k + 1], a1);
          a2 = fmaf(row[k + 2], w[k + 2], a2);
          a3 = fmaf(row[k + 3], w[k + 3], a3);
        }
        atomicAdd(&htgt[nu * HD + lane], (a0 + a1) + (a2 + a3));
      }
    }
    gridbar(nblk);   // ---- barriers 3,4,5 ----
  }

  // restore persistent globals for the next graph replay (no reader follows)
  if (blk == nblk - 1 && tid < EDIM) { g_hist[tid] = 0; g_cur[tid] = 0; }

  // ============================ phase S2S =================================
  // blocks 0 mod 4 (spreads active blocks across CUs); final h lives in hA.
  if ((blk & 3) == 0) {
    for (int gb = blk >> 2; gb < NB; gb += (nblk >> 2)) {
      int st = gstart[gb], en = gstart[gb + 1];
      int cnt = en - st;
      int cached = cnt < SMAX ? cnt : SMAX;

      int total = cached * HD;
      for (int base = tid * 4; base < total; base += 1024) {
        float4 v = *reinterpret_cast<const float4*>(hA + st * HD + base);
        int n = base >> 6, k = base & 63;
        float* row = s_hs + n * HP + k;
        row[0] = v.x; row[1] = v.y; row[2] = v.z; row[3] = v.w;
      }
      if (tid < 2 * HD) s_qstar[tid] = 0.f;
      if (tid < HD) { s_hxs[tid] = 0.f; s_cxs[tid] = 0.f; }
      __syncthreads();

      for (int it = 0; it < S2SIT; ++it) {
        // LSTM gates via transposed weights (coalesced): tid = gate index
        float acc0 = b_ih[tid] + b_hh[tid], acc1 = 0.f;
        #pragma unroll 8
        for (int j = 0; j < 2 * HD; j += 2) {
          acc0 = fmaf(s_qstar[j],     W_ihT[j * 256 + tid],       acc0);
          acc1 = fmaf(s_qstar[j + 1], W_ihT[(j + 1) * 256 + tid], acc1);
        }
        #pragma unroll 8
        for (int j = 0; j < HD; j += 2) {
          acc0 = fmaf(s_hxs[j],     W_hhT[j * 256 + tid],       acc0);
          acc1 = fmaf(s_hxs[j + 1], W_hhT[(j + 1) * 256 + tid], acc1);
        }
        s_gates[tid] = acc0 + acc1;
        __syncthreads();
        if (tid < HD) {
          float ig = sigm(s_gates[tid]);
          float fg = sigm(s_gates[HD + tid]);
          float gg = tanhf(s_gates[2 * HD + tid]);
          float og = sigm(s_gates[3 * HD + tid]);
          float c = fmaf(fg, s_cxs[tid], ig * gg);
          s_cxs[tid] = c;
          s_hxs[tid] = og * tanhf(c);
        }
        __syncthreads();

        // pass 1: per-thread dot (thread = node), padded rows
        float e = -1e30f;
        if (tid < cached) {
          const float* row = s_hs + tid * HP;
          float d0 = 0.f, d1 = 0.f;
          #pragma unroll 8
          for (int k = 0; k < HD; k += 2) {
            d0 = fmaf(row[k],     s_hxs[k],     d0);
            d1 = fmaf(row[k + 1], s_hxs[k + 1], d1);
          }
          e = d0 + d1;
          s_ebuf[tid] = e;
        }
        float m = e;
        #pragma unroll
        for (int off = 32; off; off >>= 1) m = fmaxf(m, __shfl_xor(m, off, 64));
        float qreg = s_hxs[lane];
        for (int n = cached + wv; n < cnt; n += 4) {   // overflow tail
          float ev = hA[(st + n) * HD + lane] * qreg;
          #pragma unroll
          for (int off = 32; off; off >>= 1) ev += __shfl_xor(ev, off, 64);
          m = fmaxf(m, ev);
        }
        if (lane == 0) s_redM[wv] = m;
        __syncthreads();
        float M = fmaxf(fmaxf(s_redM[0], s_redM[1]), fmaxf(s_redM[2], s_redM[3]));

        // pass 2a: a = exp(e-M), per-wave partial sum
        float sp = 0.f;
        if (tid < cached) {
          float a = expf(s_ebuf[tid] - M);
          s_ebuf[tid] = a;
          sp = a;
        }
        #pragma unroll
        for (int off = 32; off; off >>= 1) sp += __shfl_xor(sp, off, 64);
        __syncthreads();

        // pass 2b: r = sum_n a[n] * h_n (lane = feature)
        float r = 0.f;
        for (int n = wv; n < cached; n += 4)
          r = fmaf(s_ebuf[n], s_hs[n * HP + lane], r);
        float s_tail = 0.f;
        for (int n = cached + wv; n < cnt; n += 4) {   // overflow tail
          float v = hA[(st + n) * HD + lane];
          float ev = v * qreg;
          #pragma unroll
          for (int off = 32; off; off >>= 1) ev += __shfl_xor(ev, off, 64);
          float a = expf(ev - M);
          s_tail += a;
          r = fmaf(a, v, r);
        }
        if (lane == 0) s_redS[wv] = sp + s_tail;
        s_redR[wv][lane] = r;
        __syncthreads();
        if (tid < HD) {
          float S = s_redS[0] + s_redS[1] + s_redS[2] + s_redS[3];
          float R = s_redR[0][tid] + s_redR[1][tid] + s_redR[2][tid] + s_redR[3][tid];
          if (S == 0.f) S = 1.f;            // empty-graph guard (matches ref)
          s_qstar[tid] = s_hxs[tid];
          s_qstar[HD + tid] = R / S;
        }
        __syncthreads();
      }

      // output MLP
      if (tid < HD) {
        float acc = b_o1[tid];
        #pragma unroll 8
        for (int i = 0; i < 2 * HD; ++i)
          acc = fmaf(s_qstar[i], W_o1[i * HD + tid], acc);
        s_hid[tid] = acc > 0.f ? acc : 0.f;
      }
      __syncthreads();
      if (tid < HD) {
        float p = s_hid[tid] * W_o2[tid];
        #pragma unroll
        for (int off = 32; off; off >>= 1) p += __shfl_xor(p, off, 64);
        if (tid == 0) out[gb] = p + b_o2[0];
      }
      __syncthreads();
    }
  }
}

extern "C" void kernel_launch(void* const* d_in, const int* in_sizes, int n_in,
                              void* d_out, int out_size, void* d_ws, size_t ws_size,
                              hipStream_t stream) {
  const float* node_feat = (const float*)d_in[0];
  const int*   node_type = (const int*)d_in[1];
  const int*   edge_index= (const int*)d_in[2];
  const int*   edge_type = (const int*)d_in[3];
  const int*   batch     = (const int*)d_in[4];
  const float* W_emb     = (const float*)d_in[5];
  const float* b_emb     = (const float*)d_in[6];
  const float* W_e1      = (const float*)d_in[7];
  const float* b_e1      = (const float*)d_in[8];
  const float* W_e2      = (const float*)d_in[9];
  const float* b_e2      = (const float*)d_in[10];
  const float* roots     = (const float*)d_in[11];
  const float* conv_bias = (const float*)d_in[12];
  const float* W_ih      = (const float*)d_in[13];
  const float* W_hh      = (const float*)d_in[14];
  const float* b_ih      = (const float*)d_in[15];
  const float* b_hh      = (const float*)d_in[16];
  const float* W_o1      = (const float*)d_in[17];
  const float* b_o1      = (const float*)d_in[18];
  const float* W_o2      = (const float*)d_in[19];
  const float* b_o2      = (const float*)d_in[20];
  float* out = (float*)d_out;

  // workspace layout (floats/ints), base assumed 256B-aligned
  float* Wty   = (float*)d_ws;              // 5*4096
  float* hA    = Wty + EDIM * 4096;         // NN*64
  float* hB    = hA + NN * HD;              // NN*64
  float* hC    = hB + NN * HD;              // NN*64
  float* W_ihT = hC + NN * HD;              // 128*256
  float* W_hhT = W_ihT + 2 * HD * 4 * HD;   // 64*256
  int*   srcs  = (int*)(W_hhT + HD * 4 * HD); // NE
  int*   dsts  = srcs + NE;                 // NE
  int*   gstart= dsts + NE;                 // NB+1

  // grid must be co-resident for the software grid barrier. LDS (62.5 KB)
  // caps at 2 blocks/CU and __launch_bounds__(256,2) caps VGPR at 256, so
  // 512 blocks fit on 256 CUs; verify via occupancy query and fall back.
  static int grid = 0;
  if (grid == 0) {
    int maxb = 0;
    if (hipOccupancyMaxActiveBlocksPerMultiprocessor(&maxb, k_mega, 256, 0) != hipSuccess || maxb < 1)
      maxb = 1;
    grid = (maxb >= 2) ? 512 : 256;
  }

  hipLaunchKernelGGL(k_mega, dim3(grid), dim3(256), 0, stream,
                     node_feat, node_type, edge_index, edge_type, batch,
                     W_emb, b_emb, W_e1, b_e1, W_e2, b_e2, roots, conv_bias,
                     W_ih, W_hh, b_ih, b_hh, W_o1, b_o1, W_o2, b_o2,
                     Wty, hA, hB, hC, W_ihT, W_hhT, srcs, dsts, gstart, out);
}

// Round 2
// 308.325 us; speedup vs baseline: 2.0953x; 2.0953x over previous
//
#include <hip/hip_runtime.h>
#include <math.h>

// ---------------------------------------------------------------------------
// MPNNPropPred: N=20000 nodes, E=50000 edges, B=128 graphs, H=64,
// FEAT=28, N_TYPES=100, EDGE_DIM=5, MP_ITER=3, S2S_IT=4. All f32.
// R6: back to the multi-kernel regime (R5's persistent kernel collapsed
//     occupancy to 2 blocks/CU and latency-bound M phases blew up 6x).
//     Kernel count 14 -> 6 via independent-work fusion only:
//       k_setup : edgemats | W transposes | embed | edge-type histogram
//                 (ballot + device atomics) | graph starts | zero hB
//       k_place : type offsets from histogram + atomic-cursor placement
//       k_mp x3 : root (atomicAdd into zeroed target) + edge messages
//                 (wave-per-edge, W column in VGPRs, wave-uniform s_load
//                 rows) + concurrent zeroing of next iteration's target
//       k_s2s   : Set2Set + output MLP (unchanged, proven) + reset globals
//     All cross-kernel ordering via dispatch boundaries; no grid barriers.
// ---------------------------------------------------------------------------

#define NN 20000
#define NE 50000
#define NB 128
#define HD 64
#define NFEAT 28
#define NTYPES 100
#define EDIM 5
#define MPIT 3
#define S2SIT 4
#define SMAX 224                  // nodes cached in LDS (max graph ~195 expected)
#define HP (HD + 1)               // padded LDS row stride

// persistent device globals; zeroed at module load, restored to zero by
// k_s2s at the end of every graph execution (so replays stay correct).
__device__ int g_hist[EDIM] = {0, 0, 0, 0, 0};
__device__ int g_cur[EDIM]  = {0, 0, 0, 0, 0};

__device__ __forceinline__ float sigm(float x) {
  return 1.0f / (1.0f + expf(-x));
}

// --- setup: all-independent jobs fused; grid 512x256 ---
__global__ __launch_bounds__(256) void k_setup(
    const float* __restrict__ feat, const int* __restrict__ ntype,
    const int* __restrict__ etype, const int* __restrict__ batch,
    const float* __restrict__ W_emb, const float* __restrict__ b_emb,
    const float* __restrict__ W_e1, const float* __restrict__ b_e1,
    const float* __restrict__ W_e2, const float* __restrict__ b_e2,
    const float* __restrict__ W_ih, const float* __restrict__ W_hh,
    float* __restrict__ Wty, float* __restrict__ hA, float* __restrict__ hB,
    float* __restrict__ W_ihT, float* __restrict__ W_hhT,
    int* __restrict__ gstart) {
  __shared__ float v[HD];
  const int tid = threadIdx.x;
  const int lane = tid & 63;
  const int wv = tid >> 6;
  const int blk = blockIdx.x;
  const int nblk = gridDim.x;
  const int nthr = nblk << 8;
  const int gtid = (blk << 8) + tid;
  const int gw = (blk << 2) + wv;
  const int nwave = nblk << 2;

  // 1) edge-type weight matrices: Wty[t] = relu(W_e1[t]+b_e1) @ W_e2 + b_e2
  for (int u = blk; u < EDIM * 4; u += nblk) {   // blocks 0..19
    int t = u >> 2, ch = u & 3;
    if (tid < HD) {
      float x = W_e1[t * HD + tid] + b_e1[tid];
      v[tid] = x > 0.f ? x : 0.f;
    }
    __syncthreads();
    #pragma unroll
    for (int i = 0; i < 4; ++i) {
      int m = ch * 1024 + i * 256 + tid;
      float acc = b_e2[m];
      #pragma unroll
      for (int j = 0; j < HD; ++j) acc = fmaf(v[j], W_e2[j * 4096 + m], acc);
      Wty[t * 4096 + m] = acc;
    }
    __syncthreads();
  }

  // 2) LSTM weight transposes (coalesced writes)
  for (int o = gtid; o < 2 * HD * 4 * HD; o += nthr)       // W_ihT [128][256]
    W_ihT[o] = W_ih[(o & 255) * 128 + (o >> 8)];
  for (int o = gtid; o < HD * 4 * HD; o += nthr)           // W_hhT [64][256]
    W_hhT[o] = W_hh[(o & 255) * 64 + (o >> 8)];

  // 3) node embedding: wave per node, feature weights hoisted to VGPRs
  {
    float wf[NFEAT];
    #pragma unroll
    for (int f = 0; f < NFEAT; ++f) wf[f] = W_emb[(NTYPES + f) * HD + lane];
    float bb = b_emb[lane];
    for (int n = gw; n < NN; n += nwave) {
      int nu = __builtin_amdgcn_readfirstlane(n);
      int t = __builtin_amdgcn_readfirstlane(ntype[nu]);
      const float* row = feat + nu * NFEAT;        // wave-uniform -> s_load
      float acc = bb + W_emb[t * HD + lane];
      #pragma unroll
      for (int f = 0; f < NFEAT; ++f) acc = fmaf(row[f], wf[f], acc);
      hA[nu * HD + lane] = acc;
    }
  }

  // 4) edge-type histogram (ballot-aggregated device atomics)
  for (int b0 = gw; (b0 << 6) < NE; b0 += nwave) {
    int e = (b0 << 6) + lane;
    int ty = (e < NE) ? etype[e] : -1;
    #pragma unroll
    for (int t = 0; t < EDIM; ++t) {
      unsigned long long mask = __ballot(ty == t);
      if (lane == 0 && mask) atomicAdd(&g_hist[t], __popcll(mask));
    }
  }

  // 5) CSR starts for sorted batch vector
  for (int n = gtid; n < NN; n += nthr) {
    int b = batch[n];
    if (n == 0)
      for (int t = 0; t <= b; ++t) gstart[t] = 0;
    int bn = (n + 1 < NN) ? batch[n + 1] : NB;
    for (int t = b + 1; t <= bn; ++t) gstart[t] = n + 1;
  }

  // 6) zero hB (target of first MP iteration)
  {
    float4 z = make_float4(0.f, 0.f, 0.f, 0.f);
    for (int i = gtid; i < NN * HD / 4; i += nthr)
      reinterpret_cast<float4*>(hB)[i] = z;
  }
}

// --- place edges grouped by type (order within a type irrelevant) ---
__global__ __launch_bounds__(256) void k_place(
    const int* __restrict__ etype, const int* __restrict__ ei,
    int* __restrict__ srcs, int* __restrict__ dsts) {
  const int lane = threadIdx.x & 63;
  const int gw = (blockIdx.x << 2) + (threadIdx.x >> 6);
  const int nwave = gridDim.x << 2;
  int offs[EDIM];
  offs[0] = 0;
  #pragma unroll
  for (int t = 1; t < EDIM; ++t) offs[t] = offs[t - 1] + g_hist[t - 1];
  for (int b0 = gw; (b0 << 6) < NE; b0 += nwave) {
    int e = (b0 << 6) + lane;
    int ty = (e < NE) ? etype[e] : -1;
    int sv = 0, dv = 0;
    if (e < NE) { sv = ei[e]; dv = ei[NE + e]; }
    #pragma unroll
    for (int t = 0; t < EDIM; ++t) {
      unsigned long long mask = __ballot(ty == t);
      if (mask == 0ull) continue;
      int base = 0;
      if (lane == 0) base = atomicAdd(&g_cur[t], __popcll(mask));
      base = __shfl(base, 0, 64);
      if (ty == t) {
        int pos = offs[t] + base + __popcll(mask & ((1ull << lane) - 1ull));
        srcs[pos] = sv;
        dsts[pos] = dv;
      }
    }
  }
}

// --- one MP iteration: blocks 0..511 do root (atomicAdd) + zero next
//     target; blocks 512..2559 do edge messages (wave per edge).
__global__ __launch_bounds__(256) void k_mp(
    const int* __restrict__ srcs, const int* __restrict__ dsts,
    const float* __restrict__ Wty, const float* __restrict__ hsrc,
    float* __restrict__ htgt, float* __restrict__ hzero,
    const float* __restrict__ root, const float* __restrict__ bias) {
  const int lane = threadIdx.x & 63;
  const int wv = threadIdx.x >> 6;
  const int blk = blockIdx.x;

  if (blk < 512) {
    // NNConv root matvec + bias, atomicAdd into zero-initialized target
    float w[HD];
    #pragma unroll
    for (int k = 0; k < HD; ++k) w[k] = root[k * HD + lane];
    float bb = bias[lane];
    int rw = (blk << 2) + wv;                    // 0..2047
    for (int n = rw; n < NN; n += 2048) {
      int nu = __builtin_amdgcn_readfirstlane(n);
      const float* row = hsrc + nu * HD;         // wave-uniform -> s_load
      float a0 = bb, a1 = 0.f, a2 = 0.f, a3 = 0.f;
      #pragma unroll
      for (int k = 0; k < HD; k += 4) {
        a0 = fmaf(row[k + 0], w[k + 0], a0);
        a1 = fmaf(row[k + 1], w[k + 1], a1);
        a2 = fmaf(row[k + 2], w[k + 2], a2);
        a3 = fmaf(row[k + 3], w[k + 3], a3);
      }
      atomicAdd(&htgt[nu * HD + lane], (a0 + a1) + (a2 + a3));
    }
    // zero next iteration's target (independent of this phase's traffic)
    if (hzero) {
      float4 z = make_float4(0.f, 0.f, 0.f, 0.f);
      for (int i = (blk << 8) + threadIdx.x; i < NN * HD / 4; i += 512 * 256)
        reinterpret_cast<float4*>(hzero)[i] = z;
    }
  } else {
    // edge messages: hnext[dst] += h[src] @ W_{type}; one wave per edge
    int wid = ((blk - 512) << 2) + wv;           // 0..8191
    const int nw = 8192;
    int per = (NE + nw - 1) / nw;                // 7
    int beg = wid * per;
    int end = beg + per; if (end > NE) end = NE;
    if (beg >= end) return;
    int offs[EDIM + 1];
    offs[0] = 0;
    #pragma unroll
    for (int t = 0; t < EDIM; ++t) offs[t + 1] = offs[t] + g_hist[t];
    for (int t = 0; t < EDIM; ++t) {
      int lo = offs[t];     if (lo < beg) lo = beg;
      int hi = offs[t + 1]; if (hi > end) hi = end;
      if (lo >= hi) continue;
      float w[HD];
      #pragma unroll
      for (int k = 0; k < HD; ++k) w[k] = Wty[t * 4096 + k * HD + lane];
      for (int p = lo; p < hi; ++p) {
        int s = __builtin_amdgcn_readfirstlane(srcs[p]);
        int d = __builtin_amdgcn_readfirstlane(dsts[p]);
        const float* row = hsrc + s * HD;        // wave-uniform -> s_load
        float a0 = 0.f, a1 = 0.f, a2 = 0.f, a3 = 0.f;
        #pragma unroll
        for (int k = 0; k < HD; k += 4) {
          a0 = fmaf(row[k + 0], w[k + 0], a0);
          a1 = fmaf(row[k + 1], w[k + 1], a1);
          a2 = fmaf(row[k + 2], w[k + 2], a2);
          a3 = fmaf(row[k + 3], w[k + 3], a3);
        }
        atomicAdd(&htgt[d * HD + lane], (a0 + a1) + (a2 + a3));
      }
    }
  }
}

// --- Set2Set + output MLP, one block per graph (proven R4 body);
//     also restores device globals for the next graph replay.
__global__ __launch_bounds__(256) void k_s2s(
    const float* __restrict__ h, const int* __restrict__ gstart,
    const float* __restrict__ W_ihT, const float* __restrict__ W_hhT,
    const float* __restrict__ b_ih, const float* __restrict__ b_hh,
    const float* __restrict__ W_o1, const float* __restrict__ b_o1,
    const float* __restrict__ W_o2, const float* __restrict__ b_o2,
    float* __restrict__ out) {
  __shared__ float hs[SMAX * HP];     // 58240 B, padded rows
  __shared__ float ebuf[SMAX];
  __shared__ float qstar[2 * HD];
  __shared__ float hxs[HD], cxs[HD], gates[4 * HD];
  __shared__ float redM[4], redS[4], redR[4][HD];
  __shared__ float hid[HD];
  int b = blockIdx.x;
  int tid = threadIdx.x;
  int lane = tid & 63, wv = tid >> 6;

  if (b == 0 && tid < EDIM) { g_hist[tid] = 0; g_cur[tid] = 0; }  // replay reset

  int st = gstart[b], en = gstart[b + 1];
  int cnt = en - st;
  int cached = cnt < SMAX ? cnt : SMAX;

  // stage node block into padded LDS (coalesced float4 global reads)
  int total = cached * HD;
  for (int base = tid * 4; base < total; base += 1024) {
    float4 v = *reinterpret_cast<const float4*>(h + st * HD + base);
    int n = base >> 6, k = base & 63;
    float* row = hs + n * HP + k;
    row[0] = v.x; row[1] = v.y; row[2] = v.z; row[3] = v.w;
  }
  if (tid < 2 * HD) qstar[tid] = 0.f;
  if (tid < HD) { hxs[tid] = 0.f; cxs[tid] = 0.f; }
  __syncthreads();

  for (int it = 0; it < S2SIT; ++it) {
    // LSTM gates via transposed weights (coalesced): tid = gate index
    float acc0 = b_ih[tid] + b_hh[tid], acc1 = 0.f;
    #pragma unroll 8
    for (int j = 0; j < 2 * HD; j += 2) {
      acc0 = fmaf(qstar[j],     W_ihT[j * 256 + tid],       acc0);
      acc1 = fmaf(qstar[j + 1], W_ihT[(j + 1) * 256 + tid], acc1);
    }
    #pragma unroll 8
    for (int j = 0; j < HD; j += 2) {
      acc0 = fmaf(hxs[j],     W_hhT[j * 256 + tid],       acc0);
      acc1 = fmaf(hxs[j + 1], W_hhT[(j + 1) * 256 + tid], acc1);
    }
    gates[tid] = acc0 + acc1;
    __syncthreads();
    if (tid < HD) {
      float ig = sigm(gates[tid]);
      float fg = sigm(gates[HD + tid]);
      float gg = tanhf(gates[2 * HD + tid]);
      float og = sigm(gates[3 * HD + tid]);
      float c = fmaf(fg, cxs[tid], ig * gg);
      cxs[tid] = c;
      hxs[tid] = og * tanhf(c);
    }
    __syncthreads();

    // pass 1: per-thread dot (thread = node), padded LDS rows
    float e = -1e30f;
    if (tid < cached) {
      const float* row = hs + tid * HP;
      float d0 = 0.f, d1 = 0.f;
      #pragma unroll 8
      for (int k = 0; k < HD; k += 2) {
        d0 = fmaf(row[k],     hxs[k],     d0);
        d1 = fmaf(row[k + 1], hxs[k + 1], d1);
      }
      e = d0 + d1;
      ebuf[tid] = e;
    }
    float m = e;
    #pragma unroll
    for (int off = 32; off; off >>= 1) m = fmaxf(m, __shfl_xor(m, off, 64));
    float qreg = hxs[lane];
    for (int n = cached + wv; n < cnt; n += 4) {   // overflow tail
      float ev = h[(st + n) * HD + lane] * qreg;
      #pragma unroll
      for (int off = 32; off; off >>= 1) ev += __shfl_xor(ev, off, 64);
      m = fmaxf(m, ev);
    }
    if (lane == 0) redM[wv] = m;
    __syncthreads();
    float M = fmaxf(fmaxf(redM[0], redM[1]), fmaxf(redM[2], redM[3]));

    // pass 2a: a = exp(e-M), per-wave partial sum
    float sp = 0.f;
    if (tid < cached) {
      float a = expf(ebuf[tid] - M);
      ebuf[tid] = a;
      sp = a;
    }
    #pragma unroll
    for (int off = 32; off; off >>= 1) sp += __shfl_xor(sp, off, 64);
    __syncthreads();   // ebuf(a) visible to all waves

    // pass 2b: r = sum_n a[n] * h_n  (lane = feature)
    float r = 0.f;
    for (int n = wv; n < cached; n += 4)
      r = fmaf(ebuf[n], hs[n * HP + lane], r);
    float s_tail = 0.f;
    for (int n = cached + wv; n < cnt; n += 4) {   // overflow tail
      float v = h[(st + n) * HD + lane];
      float ev = v * qreg;
      #pragma unroll
      for (int off = 32; off; off >>= 1) ev += __shfl_xor(ev, off, 64);
      float a = expf(ev - M);
      s_tail += a;
      r = fmaf(a, v, r);
    }
    if (lane == 0) redS[wv] = sp + s_tail;
    redR[wv][lane] = r;
    __syncthreads();
    if (tid < HD) {
      float S = redS[0] + redS[1] + redS[2] + redS[3];
      float R = redR[0][tid] + redR[1][tid] + redR[2][tid] + redR[3][tid];
      if (S == 0.f) S = 1.f;            // empty-graph guard (matches ref)
      qstar[tid] = hxs[tid];
      qstar[HD + tid] = R / S;
    }
    __syncthreads();
  }

  // output MLP: relu(qstar @ W_o1 + b_o1) @ W_o2 + b_o2
  if (tid < HD) {
    float acc = b_o1[tid];
    #pragma unroll 8
    for (int i = 0; i < 2 * HD; ++i)
      acc = fmaf(qstar[i], W_o1[i * HD + tid], acc);
    hid[tid] = acc > 0.f ? acc : 0.f;
  }
  __syncthreads();
  if (tid < HD) {
    float p = hid[tid] * W_o2[tid];
    #pragma unroll
    for (int off = 32; off; off >>= 1) p += __shfl_xor(p, off, 64);
    if (tid == 0) out[b] = p + b_o2[0];
  }
}

extern "C" void kernel_launch(void* const* d_in, const int* in_sizes, int n_in,
                              void* d_out, int out_size, void* d_ws, size_t ws_size,
                              hipStream_t stream) {
  const float* node_feat = (const float*)d_in[0];
  const int*   node_type = (const int*)d_in[1];
  const int*   edge_index= (const int*)d_in[2];
  const int*   edge_type = (const int*)d_in[3];
  const int*   batch     = (const int*)d_in[4];
  const float* W_emb     = (const float*)d_in[5];
  const float* b_emb     = (const float*)d_in[6];
  const float* W_e1      = (const float*)d_in[7];
  const float* b_e1      = (const float*)d_in[8];
  const float* W_e2      = (const float*)d_in[9];
  const float* b_e2      = (const float*)d_in[10];
  const float* roots     = (const float*)d_in[11];
  const float* conv_bias = (const float*)d_in[12];
  const float* W_ih      = (const float*)d_in[13];
  const float* W_hh      = (const float*)d_in[14];
  const float* b_ih      = (const float*)d_in[15];
  const float* b_hh      = (const float*)d_in[16];
  const float* W_o1      = (const float*)d_in[17];
  const float* b_o1      = (const float*)d_in[18];
  const float* W_o2      = (const float*)d_in[19];
  const float* b_o2      = (const float*)d_in[20];
  float* out = (float*)d_out;

  // workspace layout (floats/ints), base assumed 256B-aligned
  float* Wty   = (float*)d_ws;              // 5*4096
  float* hA    = Wty + EDIM * 4096;         // NN*64
  float* hB    = hA + NN * HD;              // NN*64
  float* hC    = hB + NN * HD;              // NN*64
  float* W_ihT = hC + NN * HD;              // 128*256
  float* W_hhT = W_ihT + 2 * HD * 4 * HD;   // 64*256
  int*   srcs  = (int*)(W_hhT + HD * 4 * HD); // NE
  int*   dsts  = srcs + NE;                 // NE
  int*   gstart= dsts + NE;                 // NB+1

  k_setup<<<512, 256, 0, stream>>>(node_feat, node_type, edge_type, batch,
                                   W_emb, b_emb, W_e1, b_e1, W_e2, b_e2,
                                   W_ih, W_hh, Wty, hA, hB, W_ihT, W_hhT, gstart);
  k_place<<<256, 256, 0, stream>>>(edge_type, edge_index, srcs, dsts);

  // it 0: hA -> hB (zero hC) | it 1: hB -> hC (zero hA) | it 2: hC -> hA
  k_mp<<<2560, 256, 0, stream>>>(srcs, dsts, Wty, hA, hB, hC,
                                 roots + 0 * HD * HD, conv_bias + 0 * HD);
  k_mp<<<2560, 256, 0, stream>>>(srcs, dsts, Wty, hB, hC, hA,
                                 roots + 1 * HD * HD, conv_bias + 1 * HD);
  k_mp<<<2560, 256, 0, stream>>>(srcs, dsts, Wty, hC, hA, (float*)0,
                                 roots + 2 * HD * HD, conv_bias + 2 * HD);

  k_s2s<<<NB, 256, 0, stream>>>(hA, gstart, W_ihT, W_hhT, b_ih, b_hh,
                                W_o1, b_o1, W_o2, b_o2, out);
}

// Round 3
// 251.216 us; speedup vs baseline: 2.5716x; 1.2273x over previous
//
#include <hip/hip_runtime.h>
#include <math.h>

// ---------------------------------------------------------------------------
// MPNNPropPred: N=20000 nodes, E=50000 edges, B=128 graphs, H=64,
// FEAT=28, N_TYPES=100, EDGE_DIM=5, MP_ITER=3, S2S_IT=4. All f32.
// R7: remove all same-cache-line global atomics (R6's g_hist/g_cur ballot
//     counters serialized ~3900 atomics on one line each ≈ 60-80 us per
//     kernel). Back to R4's atomic-free counting sort, restructured:
//       k_setup : edgemats | W transposes | embed | per-block edge counts
//                 bc[196][5] (ballot, plain stores) | graph starts | zero hB
//       k_place : 196 fixed-range blocks; each derives its own scan base
//                 from bc (4 KB, L2) via wave reduction; block 0 writes
//                 offs[6]; in-block ballot ranks place srcs/dsts
//       k_mp x3 : root (atomicAdd into zeroed target) + edge messages
//                 (wave-per-edge, W col in VGPRs, wave-uniform s_load rows)
//                 + concurrent zeroing of next target   [offs from ws]
//       k_s2s   : Set2Set + output MLP (unchanged, proven)
//     6 dispatches, no device globals, no grid barriers.
// ---------------------------------------------------------------------------

#define NN 20000
#define NE 50000
#define NB 128
#define HD 64
#define NFEAT 28
#define NTYPES 100
#define EDIM 5
#define MPIT 3
#define S2SIT 4
#define NBLK_E ((NE + 255) / 256)  // 196 fixed-range edge blocks
#define SMAX 224                   // nodes cached in LDS (max graph ~195)
#define HP (HD + 1)                // padded LDS row stride

__device__ __forceinline__ float sigm(float x) {
  return 1.0f / (1.0f + expf(-x));
}

// --- setup: all-independent jobs fused; grid 512x256 ---
__global__ __launch_bounds__(256) void k_setup(
    const float* __restrict__ feat, const int* __restrict__ ntype,
    const int* __restrict__ etype, const int* __restrict__ batch,
    const float* __restrict__ W_emb, const float* __restrict__ b_emb,
    const float* __restrict__ W_e1, const float* __restrict__ b_e1,
    const float* __restrict__ W_e2, const float* __restrict__ b_e2,
    const float* __restrict__ W_ih, const float* __restrict__ W_hh,
    float* __restrict__ Wty, float* __restrict__ hA, float* __restrict__ hB,
    float* __restrict__ W_ihT, float* __restrict__ W_hhT,
    int* __restrict__ gstart, int* __restrict__ bc) {
  __shared__ float v[HD];
  __shared__ int wcc[4][EDIM];
  const int tid = threadIdx.x;
  const int lane = tid & 63;
  const int wv = tid >> 6;
  const int blk = blockIdx.x;
  const int nblk = gridDim.x;
  const int nthr = nblk << 8;
  const int gtid = (blk << 8) + tid;
  const int gw = (blk << 2) + wv;
  const int nwave = nblk << 2;

  // 1) per-block edge-type counts (atomic-free; blocks 0..195)
  if (blk < NBLK_E) {
    int e = (blk << 8) + tid;
    int ty = (e < NE) ? etype[e] : -1;
    #pragma unroll
    for (int t = 0; t < EDIM; ++t) {
      unsigned long long m = __ballot(ty == t);
      if (lane == 0) wcc[wv][t] = __popcll(m);
    }
    __syncthreads();
    if (tid < EDIM) {
      int s = wcc[0][tid] + wcc[1][tid] + wcc[2][tid] + wcc[3][tid];
      bc[blk * EDIM + tid] = s;
    }
    __syncthreads();
  }

  // 2) edge-type weight matrices: Wty[t] = relu(W_e1[t]+b_e1) @ W_e2 + b_e2
  for (int u = blk; u < EDIM * 4; u += nblk) {   // blocks 0..19
    int t = u >> 2, ch = u & 3;
    if (tid < HD) {
      float x = W_e1[t * HD + tid] + b_e1[tid];
      v[tid] = x > 0.f ? x : 0.f;
    }
    __syncthreads();
    #pragma unroll
    for (int i = 0; i < 4; ++i) {
      int m = ch * 1024 + i * 256 + tid;
      float acc = b_e2[m];
      #pragma unroll
      for (int j = 0; j < HD; ++j) acc = fmaf(v[j], W_e2[j * 4096 + m], acc);
      Wty[t * 4096 + m] = acc;
    }
    __syncthreads();
  }

  // 3) LSTM weight transposes (coalesced writes)
  for (int o = gtid; o < 2 * HD * 4 * HD; o += nthr)       // W_ihT [128][256]
    W_ihT[o] = W_ih[(o & 255) * 128 + (o >> 8)];
  for (int o = gtid; o < HD * 4 * HD; o += nthr)           // W_hhT [64][256]
    W_hhT[o] = W_hh[(o & 255) * 64 + (o >> 8)];

  // 4) node embedding: wave per node, feature weights hoisted to VGPRs
  {
    float wf[NFEAT];
    #pragma unroll
    for (int f = 0; f < NFEAT; ++f) wf[f] = W_emb[(NTYPES + f) * HD + lane];
    float bb = b_emb[lane];
    for (int n = gw; n < NN; n += nwave) {
      int nu = __builtin_amdgcn_readfirstlane(n);
      int t = __builtin_amdgcn_readfirstlane(ntype[nu]);
      const float* row = feat + nu * NFEAT;        // wave-uniform -> s_load
      float acc = bb + W_emb[t * HD + lane];
      #pragma unroll
      for (int f = 0; f < NFEAT; ++f) acc = fmaf(row[f], wf[f], acc);
      hA[nu * HD + lane] = acc;
    }
  }

  // 5) CSR starts for sorted batch vector
  for (int n = gtid; n < NN; n += nthr) {
    int b = batch[n];
    if (n == 0)
      for (int t = 0; t <= b; ++t) gstart[t] = 0;
    int bn = (n + 1 < NN) ? batch[n + 1] : NB;
    for (int t = b + 1; t <= bn; ++t) gstart[t] = n + 1;
  }

  // 6) zero hB (target of first MP iteration)
  {
    float4 z = make_float4(0.f, 0.f, 0.f, 0.f);
    for (int i = gtid; i < NN * HD / 4; i += nthr)
      reinterpret_cast<float4*>(hB)[i] = z;
  }
}

// --- place edges grouped by type; each block derives its scan base from bc.
__global__ __launch_bounds__(256) void k_place(
    const int* __restrict__ etype, const int* __restrict__ ei,
    const int* __restrict__ bc,
    int* __restrict__ srcs, int* __restrict__ dsts, int* __restrict__ offs_out) {
  __shared__ int s_base[EDIM];      // this block's placement base per type
  __shared__ int wc[4][EDIM];
  const int tid = threadIdx.x;
  const int lane = tid & 63;
  const int wv = tid >> 6;
  const int blk = blockIdx.x;

  // wave 0: per-type totals and prefix-below-blk from bc (L2-resident 4 KB)
  if (wv == 0) {
    int part[EDIM], tot[EDIM];
    #pragma unroll
    for (int t = 0; t < EDIM; ++t) { part[t] = 0; tot[t] = 0; }
    for (int b = lane; b < NBLK_E; b += 64) {
      #pragma unroll
      for (int t = 0; t < EDIM; ++t) {
        int x = bc[b * EDIM + t];
        tot[t] += x;
        if (b < blk) part[t] += x;
      }
    }
    #pragma unroll
    for (int t = 0; t < EDIM; ++t) {
      #pragma unroll
      for (int off = 32; off; off >>= 1) {
        tot[t]  += __shfl_xor(tot[t],  off, 64);
        part[t] += __shfl_xor(part[t], off, 64);
      }
    }
    if (lane == 0) {
      int run = 0;
      #pragma unroll
      for (int t = 0; t < EDIM; ++t) {
        s_base[t] = run + part[t];
        if (blk == 0) offs_out[t] = run;
        run += tot[t];
      }
      if (blk == 0) offs_out[EDIM] = run;
    }
  }

  // all waves: ballot ranks within the block's fixed 256-edge range
  int e = (blk << 8) + tid;
  int ty = (e < NE) ? etype[e] : -1;
  int sv = 0, dv = 0;
  if (e < NE) { sv = ei[e]; dv = ei[NE + e]; }
  int rank = 0;
  #pragma unroll
  for (int t = 0; t < EDIM; ++t) {
    unsigned long long m = __ballot(ty == t);
    if (lane == 0) wc[wv][t] = __popcll(m);
    if (ty == t) rank = __popcll(m & ((1ull << lane) - 1ull));
  }
  __syncthreads();
  if (ty >= 0) {
    int base = s_base[ty];
    for (int w = 0; w < wv; ++w) base += wc[w][ty];
    srcs[base + rank] = sv;
    dsts[base + rank] = dv;
  }
}

// --- one MP iteration: blocks 0..511 do root (atomicAdd) + zero next
//     target; blocks 512..2559 do edge messages (wave per edge).
__global__ __launch_bounds__(256) void k_mp(
    const int* __restrict__ srcs, const int* __restrict__ dsts,
    const int* __restrict__ offs_in,
    const float* __restrict__ Wty, const float* __restrict__ hsrc,
    float* __restrict__ htgt, float* __restrict__ hzero,
    const float* __restrict__ root, const float* __restrict__ bias) {
  const int lane = threadIdx.x & 63;
  const int wv = threadIdx.x >> 6;
  const int blk = blockIdx.x;

  if (blk < 512) {
    // NNConv root matvec + bias, atomicAdd into zero-initialized target
    float w[HD];
    #pragma unroll
    for (int k = 0; k < HD; ++k) w[k] = root[k * HD + lane];
    float bb = bias[lane];
    int rw = (blk << 2) + wv;                    // 0..2047
    for (int n = rw; n < NN; n += 2048) {
      int nu = __builtin_amdgcn_readfirstlane(n);
      const float* row = hsrc + nu * HD;         // wave-uniform -> s_load
      float a0 = bb, a1 = 0.f, a2 = 0.f, a3 = 0.f;
      #pragma unroll
      for (int k = 0; k < HD; k += 4) {
        a0 = fmaf(row[k + 0], w[k + 0], a0);
        a1 = fmaf(row[k + 1], w[k + 1], a1);
        a2 = fmaf(row[k + 2], w[k + 2], a2);
        a3 = fmaf(row[k + 3], w[k + 3], a3);
      }
      atomicAdd(&htgt[nu * HD + lane], (a0 + a1) + (a2 + a3));
    }
    // zero next iteration's target (independent of this phase's traffic)
    if (hzero) {
      float4 z = make_float4(0.f, 0.f, 0.f, 0.f);
      for (int i = (blk << 8) + threadIdx.x; i < NN * HD / 4; i += 512 * 256)
        reinterpret_cast<float4*>(hzero)[i] = z;
    }
  } else {
    // edge messages: hnext[dst] += h[src] @ W_{type}; one wave per edge
    int wid = ((blk - 512) << 2) + wv;           // 0..8191
    const int nw = 8192;
    int per = (NE + nw - 1) / nw;                // 7
    int beg = wid * per;
    int end = beg + per; if (end > NE) end = NE;
    if (beg >= end) return;
    int offs[EDIM + 1];
    #pragma unroll
    for (int t = 0; t <= EDIM; ++t) offs[t] = offs_in[t];
    for (int t = 0; t < EDIM; ++t) {
      int lo = offs[t];     if (lo < beg) lo = beg;
      int hi = offs[t + 1]; if (hi > end) hi = end;
      if (lo >= hi) continue;
      float w[HD];
      #pragma unroll
      for (int k = 0; k < HD; ++k) w[k] = Wty[t * 4096 + k * HD + lane];
      for (int p = lo; p < hi; ++p) {
        int s = __builtin_amdgcn_readfirstlane(srcs[p]);
        int d = __builtin_amdgcn_readfirstlane(dsts[p]);
        const float* row = hsrc + s * HD;        // wave-uniform -> s_load
        float a0 = 0.f, a1 = 0.f, a2 = 0.f, a3 = 0.f;
        #pragma unroll
        for (int k = 0; k < HD; k += 4) {
          a0 = fmaf(row[k + 0], w[k + 0], a0);
          a1 = fmaf(row[k + 1], w[k + 1], a1);
          a2 = fmaf(row[k + 2], w[k + 2], a2);
          a3 = fmaf(row[k + 3], w[k + 3], a3);
        }
        atomicAdd(&htgt[d * HD + lane], (a0 + a1) + (a2 + a3));
      }
    }
  }
}

// --- Set2Set + output MLP, one block per graph (proven R4 body) ---
__global__ __launch_bounds__(256) void k_s2s(
    const float* __restrict__ h, const int* __restrict__ gstart,
    const float* __restrict__ W_ihT, const float* __restrict__ W_hhT,
    const float* __restrict__ b_ih, const float* __restrict__ b_hh,
    const float* __restrict__ W_o1, const float* __restrict__ b_o1,
    const float* __restrict__ W_o2, const float* __restrict__ b_o2,
    float* __restrict__ out) {
  __shared__ float hs[SMAX * HP];     // 58240 B, padded rows
  __shared__ float ebuf[SMAX];
  __shared__ float qstar[2 * HD];
  __shared__ float hxs[HD], cxs[HD], gates[4 * HD];
  __shared__ float redM[4], redS[4], redR[4][HD];
  __shared__ float hid[HD];
  int b = blockIdx.x;
  int tid = threadIdx.x;
  int lane = tid & 63, wv = tid >> 6;

  int st = gstart[b], en = gstart[b + 1];
  int cnt = en - st;
  int cached = cnt < SMAX ? cnt : SMAX;

  // stage node block into padded LDS (coalesced float4 global reads)
  int total = cached * HD;
  for (int base = tid * 4; base < total; base += 1024) {
    float4 v = *reinterpret_cast<const float4*>(h + st * HD + base);
    int n = base >> 6, k = base & 63;
    float* row = hs + n * HP + k;
    row[0] = v.x; row[1] = v.y; row[2] = v.z; row[3] = v.w;
  }
  if (tid < 2 * HD) qstar[tid] = 0.f;
  if (tid < HD) { hxs[tid] = 0.f; cxs[tid] = 0.f; }
  __syncthreads();

  for (int it = 0; it < S2SIT; ++it) {
    // LSTM gates via transposed weights (coalesced): tid = gate index
    float acc0 = b_ih[tid] + b_hh[tid], acc1 = 0.f;
    #pragma unroll 8
    for (int j = 0; j < 2 * HD; j += 2) {
      acc0 = fmaf(qstar[j],     W_ihT[j * 256 + tid],       acc0);
      acc1 = fmaf(qstar[j + 1], W_ihT[(j + 1) * 256 + tid], acc1);
    }
    #pragma unroll 8
    for (int j = 0; j < HD; j += 2) {
      acc0 = fmaf(hxs[j],     W_hhT[j * 256 + tid],       acc0);
      acc1 = fmaf(hxs[j + 1], W_hhT[(j + 1) * 256 + tid], acc1);
    }
    gates[tid] = acc0 + acc1;
    __syncthreads();
    if (tid < HD) {
      float ig = sigm(gates[tid]);
      float fg = sigm(gates[HD + tid]);
      float gg = tanhf(gates[2 * HD + tid]);
      float og = sigm(gates[3 * HD + tid]);
      float c = fmaf(fg, cxs[tid], ig * gg);
      cxs[tid] = c;
      hxs[tid] = og * tanhf(c);
    }
    __syncthreads();

    // pass 1: per-thread dot (thread = node), padded LDS rows
    float e = -1e30f;
    if (tid < cached) {
      const float* row = hs + tid * HP;
      float d0 = 0.f, d1 = 0.f;
      #pragma unroll 8
      for (int k = 0; k < HD; k += 2) {
        d0 = fmaf(row[k],     hxs[k],     d0);
        d1 = fmaf(row[k + 1], hxs[k + 1], d1);
      }
      e = d0 + d1;
      ebuf[tid] = e;
    }
    float m = e;
    #pragma unroll
    for (int off = 32; off; off >>= 1) m = fmaxf(m, __shfl_xor(m, off, 64));
    float qreg = hxs[lane];
    for (int n = cached + wv; n < cnt; n += 4) {   // overflow tail
      float ev = h[(st + n) * HD + lane] * qreg;
      #pragma unroll
      for (int off = 32; off; off >>= 1) ev += __shfl_xor(ev, off, 64);
      m = fmaxf(m, ev);
    }
    if (lane == 0) redM[wv] = m;
    __syncthreads();
    float M = fmaxf(fmaxf(redM[0], redM[1]), fmaxf(redM[2], redM[3]));

    // pass 2a: a = exp(e-M), per-wave partial sum
    float sp = 0.f;
    if (tid < cached) {
      float a = expf(ebuf[tid] - M);
      ebuf[tid] = a;
      sp = a;
    }
    #pragma unroll
    for (int off = 32; off; off >>= 1) sp += __shfl_xor(sp, off, 64);
    __syncthreads();   // ebuf(a) visible to all waves

    // pass 2b: r = sum_n a[n] * h_n  (lane = feature)
    float r = 0.f;
    for (int n = wv; n < cached; n += 4)
      r = fmaf(ebuf[n], hs[n * HP + lane], r);
    float s_tail = 0.f;
    for (int n = cached + wv; n < cnt; n += 4) {   // overflow tail
      float v = h[(st + n) * HD + lane];
      float ev = v * qreg;
      #pragma unroll
      for (int off = 32; off; off >>= 1) ev += __shfl_xor(ev, off, 64);
      float a = expf(ev - M);
      s_tail += a;
      r = fmaf(a, v, r);
    }
    if (lane == 0) redS[wv] = sp + s_tail;
    redR[wv][lane] = r;
    __syncthreads();
    if (tid < HD) {
      float S = redS[0] + redS[1] + redS[2] + redS[3];
      float R = redR[0][tid] + redR[1][tid] + redR[2][tid] + redR[3][tid];
      if (S == 0.f) S = 1.f;            // empty-graph guard (matches ref)
      qstar[tid] = hxs[tid];
      qstar[HD + tid] = R / S;
    }
    __syncthreads();
  }

  // output MLP: relu(qstar @ W_o1 + b_o1) @ W_o2 + b_o2
  if (tid < HD) {
    float acc = b_o1[tid];
    #pragma unroll 8
    for (int i = 0; i < 2 * HD; ++i)
      acc = fmaf(qstar[i], W_o1[i * HD + tid], acc);
    hid[tid] = acc > 0.f ? acc : 0.f;
  }
  __syncthreads();
  if (tid < HD) {
    float p = hid[tid] * W_o2[tid];
    #pragma unroll
    for (int off = 32; off; off >>= 1) p += __shfl_xor(p, off, 64);
    if (tid == 0) out[b] = p + b_o2[0];
  }
}

extern "C" void kernel_launch(void* const* d_in, const int* in_sizes, int n_in,
                              void* d_out, int out_size, void* d_ws, size_t ws_size,
                              hipStream_t stream) {
  const float* node_feat = (const float*)d_in[0];
  const int*   node_type = (const int*)d_in[1];
  const int*   edge_index= (const int*)d_in[2];
  const int*   edge_type = (const int*)d_in[3];
  const int*   batch     = (const int*)d_in[4];
  const float* W_emb     = (const float*)d_in[5];
  const float* b_emb     = (const float*)d_in[6];
  const float* W_e1      = (const float*)d_in[7];
  const float* b_e1      = (const float*)d_in[8];
  const float* W_e2      = (const float*)d_in[9];
  const float* b_e2      = (const float*)d_in[10];
  const float* roots     = (const float*)d_in[11];
  const float* conv_bias = (const float*)d_in[12];
  const float* W_ih      = (const float*)d_in[13];
  const float* W_hh      = (const float*)d_in[14];
  const float* b_ih      = (const float*)d_in[15];
  const float* b_hh      = (const float*)d_in[16];
  const float* W_o1      = (const float*)d_in[17];
  const float* b_o1      = (const float*)d_in[18];
  const float* W_o2      = (const float*)d_in[19];
  const float* b_o2      = (const float*)d_in[20];
  float* out = (float*)d_out;

  // workspace layout (floats/ints), base assumed 256B-aligned
  float* Wty   = (float*)d_ws;              // 5*4096
  float* hA    = Wty + EDIM * 4096;         // NN*64
  float* hB    = hA + NN * HD;              // NN*64
  float* hC    = hB + NN * HD;              // NN*64
  float* W_ihT = hC + NN * HD;              // 128*256
  float* W_hhT = W_ihT + 2 * HD * 4 * HD;   // 64*256
  int*   srcs  = (int*)(W_hhT + HD * 4 * HD); // NE
  int*   dsts  = srcs + NE;                 // NE
  int*   gstart= dsts + NE;                 // NB+1 (pad to 136)
  int*   bc    = gstart + 136;              // NBLK_E*EDIM
  int*   offs  = bc + NBLK_E * EDIM;        // EDIM+1

  k_setup<<<512, 256, 0, stream>>>(node_feat, node_type, edge_type, batch,
                                   W_emb, b_emb, W_e1, b_e1, W_e2, b_e2,
                                   W_ih, W_hh, Wty, hA, hB, W_ihT, W_hhT,
                                   gstart, bc);
  k_place<<<NBLK_E, 256, 0, stream>>>(edge_type, edge_index, bc, srcs, dsts, offs);

  // it 0: hA -> hB (zero hC) | it 1: hB -> hC (zero hA) | it 2: hC -> hA
  k_mp<<<2560, 256, 0, stream>>>(srcs, dsts, offs, Wty, hA, hB, hC,
                                 roots + 0 * HD * HD, conv_bias + 0 * HD);
  k_mp<<<2560, 256, 0, stream>>>(srcs, dsts, offs, Wty, hB, hC, hA,
                                 roots + 1 * HD * HD, conv_bias + 1 * HD);
  k_mp<<<2560, 256, 0, stream>>>(srcs, dsts, offs, Wty, hC, hA, (float*)0,
                                 roots + 2 * HD * HD, conv_bias + 2 * HD);

  k_s2s<<<NB, 256, 0, stream>>>(hA, gstart, W_ihT, W_hhT, b_ih, b_hh,
                                W_o1, b_o1, W_o2, b_o2, out);
}